// Round 10
// baseline (211.212 us; speedup 1.0000x reference)
//
#include <hip/hip_runtime.h>

// NavierStokesLossMAC: B=8, H=W=1024
//   d_in[0] v_old (B,2,H,W) f32 | d_in[1] v_new (B,2,H,W) f32
//   d_in[2] p_new (B,1,H,W) f32 | d_in[3] mask  (B,1,H,W) i32
// out: (B,) f32
//
// R18: producer/consumer split-role block. R17 proved fill rate scales with
// free-running wave concurrency (~1.8 GB/s/CU per wave, saturating ~19 at
// 11+ waves): its clean {204 MB, no-spill, deep-pipeline} kernel lost
// because barrier pacing left 4 waves/CU -> 9.5 GB/s/CU. R11 = {352 MB,
// 10.6 waves} = 73us. Win condition: fewer bytes AND >=10 free-running
// waves AND <=21 live f4/thread. This kernel:
//  * 512-thr block, 4 full-width rows. Half0 (waves 0-3) == R11 thread:
//    21-load burst rows y-1..y+2, computes y,y+1. Half1 (waves 4-7): only
//    NEW data (12 f4: v y+3,y+4; p y+2,y+3; m y+2,y+3), computes y+2,y+3.
//  * Half0 publishes u,w rows y+1,y+2 + du,dw row y+2 + p row y+1 (28KB
//    LDS) across ONE raw s_barrier. Half1's loads stay in flight over it.
//    No loop barriers anywhere -> free-running like R11.
//  * 33 f4 / 4 rows = 276 MB requested (-22% vs R11). Neither path holds
//    >21 live f4 -> no spill (canary: WRITE_SIZE KB-scale, VGPR<=96).
//  * launch_bounds(512,3) -> 3 blocks/CU = 24 waves/CU.
//  * row y+2 x-neighbors read directly from full LDS rows; remaining seams
//    R8-style predicated scalar loads (instr count irrelevant, R10).
//  * XCD-bijective swizzle (2048 % 8 == 0).

#define NS_H 1024
#define NS_W 1024
#define RPB 4
#define NBY 256                       // 4-row chunks per batch
#define NBLK (8 * NBY)
#define PARTS_PER_B NBY

__device__ __forceinline__ float4 ld4(const float* p) { return *(const float4*)p; }
__device__ __forceinline__ int4  ld4i(const int* p)   { return *(const int4*)p; }
__device__ __forceinline__ float4 avg4(float4 a, float4 b) {
    return make_float4(0.5f*(a.x+b.x), 0.5f*(a.y+b.y), 0.5f*(a.z+b.z), 0.5f*(a.w+b.w));
}
__device__ __forceinline__ float4 sub4(float4 a, float4 b) {
    return make_float4(a.x-b.x, a.y-b.y, a.z-b.z, a.w-b.w);
}

__device__ __forceinline__ float row_stencil(
    const float uc[6], const float wcv[6],
    const float uym[4], const float uyp[4],
    const float wym[4], const float wyp[4],
    const float du[4], const float dw[4],
    const float pcv[5], const float pym[4],
    const int mm[4], int xbase, float rv)
{
    float acc = 0.f;
    #pragma unroll
    for (int j = 0; j < 4; ++j) {
        const int x = xbase + j;
        const float m = ((x >= 1 && x <= NS_W - 2) ? (float)mm[j] : 0.f) * rv;
        const float u_cc = uc[j+1],  u_xm = uc[j],  u_xp = uc[j+2];
        const float w_cc = wcv[j+1], w_xm = wcv[j], w_xp = wcv[j+2];

        float res_x =
            dw[j] * 0.25f
          + w_cc * 0.5f * (w_xp - w_xm)
          + 0.5f * ( 0.5f * (u_cc + u_xm) * (w_cc   - wym[j])
                   + 0.5f * (u_cc + u_xp) * (wyp[j] - w_cc  ) )
          + (pcv[j+1] - pcv[j])
          - 0.1f * (w_xm + w_xp + wym[j] + wyp[j] - 4.f * w_cc);

        float res_y =
            du[j] * 0.25f
          + u_cc * 0.5f * (uyp[j] - uym[j])
          + 0.5f * ( 0.5f * (w_cc + wym[j]) * (u_cc - u_xm)
                   + 0.5f * (w_cc + wyp[j]) * (u_xp - u_cc) )
          + (pcv[j+1] - pym[j])
          - 0.1f * (u_xm + u_xp + uym[j] + uyp[j] - 4.f * u_cc);

        acc += m * (res_x * res_x + res_y * res_y);
    }
    return acc;
}

__global__ __launch_bounds__(512, 3) void ns_loss_partial(
    const float* __restrict__ v_old,
    const float* __restrict__ v_new,
    const float* __restrict__ p,
    const int*   __restrict__ mask,
    float* __restrict__ ws)
{
    // XCD-bijective swizzle over 2048 blocks
    const int blkp = blockIdx.x;
    const int lg   = (blkp & 7) * NBY + (blkp >> 3);
    const int b    = lg >> 8;
    const int cy   = lg & 255;
    const int y0   = 1 + cy * RPB;      // rows y0..y0+3 (tail rows validity-masked)

    const size_t hw = (size_t)NS_H * NS_W;
    const float* uo = v_old + (size_t)b * 2 * hw;
    const float* wo = uo + hw;
    const float* un = v_new + (size_t)b * 2 * hw;
    const float* wn = un + hw;
    const float* pb = p    + (size_t)b * hw;
    const int*   mb = mask + (size_t)b * hw;

    const int tid  = (int)threadIdx.x;     // 0..511
    const int h    = tid >> 8;             // half: 0 producer, 1 consumer
    const int t    = tid & 255;
    const int lane = tid & 63;
    const int q0   = t * 4;                // global col 0..1020
    const bool seamL = (lane == 0)  && (q0 > 0);
    const bool seamR = (lane == 63) && (q0 + 4 < NS_W);

    const int rm = (y0 - 1) * NS_W;
    const int rc = rm + NS_W;              // y0      <= 1021
    const int rp = rc + NS_W;              // y0+1    <= 1022
    const int rq = rp + NS_W;              // y0+2    <= 1023
    int Rr = y0 + 3; if (Rr > 1023) Rr = 1023;
    int Rs = y0 + 4; if (Rs > 1023) Rs = 1023;
    const int rr = Rr * NS_W;
    const int rs = Rs * NS_W;
    const float rv_q = (y0 + 2 <= NS_H - 2) ? 1.f : 0.f;
    const float rv_r = (y0 + 3 <= NS_H - 2) ? 1.f : 0.f;

    // producer -> consumer hand-off: full 1024-wide derived rows
    // 0:u(y+1) 1:w(y+1) 2:u(y+2) 3:w(y+2) 4:du(y+2) 5:dw(y+2) 6:p(y+1)
    __shared__ float shr[7][1024];
    __shared__ float sred[8];

    float acc = 0.f;

    if (h == 0) {
        // ================= PRODUCER: R11 thread verbatim =================
        float4 un_m = ld4(un + rm + q0), uo_m = ld4(uo + rm + q0);
        float4 un_c = ld4(un + rc + q0), uo_c = ld4(uo + rc + q0);
        float4 un_p = ld4(un + rp + q0), uo_p = ld4(uo + rp + q0);
        float4 un_q = ld4(un + rq + q0), uo_q = ld4(uo + rq + q0);
        float4 wn_m = ld4(wn + rm + q0), wo_m = ld4(wo + rm + q0);
        float4 wn_c = ld4(wn + rc + q0), wo_c = ld4(wo + rc + q0);
        float4 wn_p = ld4(wn + rp + q0), wo_p = ld4(wo + rp + q0);
        float4 wn_q = ld4(wn + rq + q0), wo_q = ld4(wo + rq + q0);
        float4 p_m4 = ld4(pb + rm + q0);
        float4 p_c4 = ld4(pb + rc + q0);
        float4 p_p4 = ld4(pb + rp + q0);
        int4   m_c4 = ld4i(mb + rc + q0);
        int4   m_p4 = ld4i(mb + rp + q0);

        // R8-style seam scalars for rows rc,rp
        float sulc = 0.f, swlc = 0.f, splc = 0.f, sulp = 0.f, swlp = 0.f, splp = 0.f;
        float surc = 0.f, swrc = 0.f, surp = 0.f, swrp = 0.f;
        if (seamL) {
            sulc = 0.5f * (un[rc + q0 - 1] + uo[rc + q0 - 1]);
            swlc = 0.5f * (wn[rc + q0 - 1] + wo[rc + q0 - 1]);
            splc = pb[rc + q0 - 1];
            sulp = 0.5f * (un[rp + q0 - 1] + uo[rp + q0 - 1]);
            swlp = 0.5f * (wn[rp + q0 - 1] + wo[rp + q0 - 1]);
            splp = pb[rp + q0 - 1];
        }
        if (seamR) {
            surc = 0.5f * (un[rc + q0 + 4] + uo[rc + q0 + 4]);
            swrc = 0.5f * (wn[rc + q0 + 4] + wo[rc + q0 + 4]);
            surp = 0.5f * (un[rp + q0 + 4] + uo[rp + q0 + 4]);
            swrp = 0.5f * (wn[rp + q0 + 4] + wo[rp + q0 + 4]);
        }
        __builtin_amdgcn_sched_barrier(0);

        float4 u_m = avg4(un_m, uo_m), u_c = avg4(un_c, uo_c);
        float4 u_p = avg4(un_p, uo_p), u_q = avg4(un_q, uo_q);
        float4 w_m = avg4(wn_m, wo_m), w_c = avg4(wn_c, wo_c);
        float4 w_p = avg4(wn_p, wo_p), w_q = avg4(wn_q, wo_q);
        float4 du_c = sub4(un_c, uo_c), du_p = sub4(un_p, uo_p);
        float4 dw_c = sub4(wn_c, wo_c), dw_p = sub4(wn_p, wo_p);
        float4 du_q = sub4(un_q, uo_q), dw_q = sub4(wn_q, wo_q);

        // publish hand-off rows
        *(float4*)&shr[0][q0] = u_p;  *(float4*)&shr[1][q0] = w_p;
        *(float4*)&shr[2][q0] = u_q;  *(float4*)&shr[3][q0] = w_q;
        *(float4*)&shr[4][q0] = du_q; *(float4*)&shr[5][q0] = dw_q;
        *(float4*)&shr[6][q0] = p_p4;
        __builtin_amdgcn_sched_barrier(0);
        asm volatile("s_waitcnt lgkmcnt(0)" ::: "memory");
        __builtin_amdgcn_s_barrier();
        __builtin_amdgcn_sched_barrier(0);

        // seams via shfl + overrides
        float ul_c = __shfl_up(u_c.w, 1),  wl_c = __shfl_up(w_c.w, 1);
        float ul_p = __shfl_up(u_p.w, 1),  wl_p = __shfl_up(w_p.w, 1);
        float pl_c = __shfl_up(p_c4.w, 1), pl_p = __shfl_up(p_p4.w, 1);
        if (lane == 0) { ul_c = sulc; wl_c = swlc; pl_c = splc;
                         ul_p = sulp; wl_p = swlp; pl_p = splp; }
        float ur_c = __shfl_down(u_c.x, 1), wr_c = __shfl_down(w_c.x, 1);
        float ur_p = __shfl_down(u_p.x, 1), wr_p = __shfl_down(w_p.x, 1);
        if (lane == 63) { ur_c = surc; wr_c = swrc; ur_p = surp; wr_p = swrp; }

        {
            const float uc[6]  = {ul_c, u_c.x, u_c.y, u_c.z, u_c.w, ur_c};
            const float wcv[6] = {wl_c, w_c.x, w_c.y, w_c.z, w_c.w, wr_c};
            const float uym[4] = {u_m.x, u_m.y, u_m.z, u_m.w};
            const float uyp[4] = {u_p.x, u_p.y, u_p.z, u_p.w};
            const float wym[4] = {w_m.x, w_m.y, w_m.z, w_m.w};
            const float wyp[4] = {w_p.x, w_p.y, w_p.z, w_p.w};
            const float du[4]  = {du_c.x, du_c.y, du_c.z, du_c.w};
            const float dw[4]  = {dw_c.x, dw_c.y, dw_c.z, dw_c.w};
            const float pcv[5] = {pl_c, p_c4.x, p_c4.y, p_c4.z, p_c4.w};
            const float pym[4] = {p_m4.x, p_m4.y, p_m4.z, p_m4.w};
            const int   mm[4]  = {m_c4.x, m_c4.y, m_c4.z, m_c4.w};
            acc += row_stencil(uc, wcv, uym, uyp, wym, wyp, du, dw, pcv, pym, mm, q0, 1.f);
        }
        {
            const float uc[6]  = {ul_p, u_p.x, u_p.y, u_p.z, u_p.w, ur_p};
            const float wcv[6] = {wl_p, w_p.x, w_p.y, w_p.z, w_p.w, wr_p};
            const float uym[4] = {u_c.x, u_c.y, u_c.z, u_c.w};
            const float uyp[4] = {u_q.x, u_q.y, u_q.z, u_q.w};
            const float wym[4] = {w_c.x, w_c.y, w_c.z, w_c.w};
            const float wyp[4] = {w_q.x, w_q.y, w_q.z, w_q.w};
            const float du[4]  = {du_p.x, du_p.y, du_p.z, du_p.w};
            const float dw[4]  = {dw_p.x, dw_p.y, dw_p.z, dw_p.w};
            const float pcv[5] = {pl_p, p_p4.x, p_p4.y, p_p4.z, p_p4.w};
            const float pym[4] = {p_c4.x, p_c4.y, p_c4.z, p_c4.w};
            const int   mm[4]  = {m_p4.x, m_p4.y, m_p4.z, m_p4.w};
            acc += row_stencil(uc, wcv, uym, uyp, wym, wyp, du, dw, pcv, pym, mm, q0, 1.f);
        }
    } else {
        // ================= CONSUMER: only NEW data =================
        float4 un_r = ld4(un + rr + q0), uo_r = ld4(uo + rr + q0);
        float4 wn_r = ld4(wn + rr + q0), wo_r = ld4(wo + rr + q0);
        float4 un_s = ld4(un + rs + q0), uo_s = ld4(uo + rs + q0);
        float4 wn_s = ld4(wn + rs + q0), wo_s = ld4(wo + rs + q0);
        float4 p_q4 = ld4(pb + rq + q0);
        float4 p_r4 = ld4(pb + rr + q0);
        int4   m_q4 = ld4i(mb + rq + q0);
        int4   m_r4 = ld4i(mb + rr + q0);

        float sulr = 0.f, swlr = 0.f, splr = 0.f, splq = 0.f;
        float surr = 0.f, swrr = 0.f;
        if (seamL) {
            sulr = 0.5f * (un[rr + q0 - 1] + uo[rr + q0 - 1]);
            swlr = 0.5f * (wn[rr + q0 - 1] + wo[rr + q0 - 1]);
            splr = pb[rr + q0 - 1];
            splq = pb[rq + q0 - 1];
        }
        if (seamR) {
            surr = 0.5f * (un[rr + q0 + 4] + uo[rr + q0 + 4]);
            swrr = 0.5f * (wn[rr + q0 + 4] + wo[rr + q0 + 4]);
        }
        __builtin_amdgcn_sched_barrier(0);
        __builtin_amdgcn_s_barrier();          // raw: own loads stay in flight
        __builtin_amdgcn_sched_barrier(0);

        // hand-off reads (full rows -> x-neighbors direct)
        const int il = (q0 > 0) ? q0 - 1 : 0;          // clamped; edges masked
        const int ir = (q0 + 4 < NS_W) ? q0 + 4 : NS_W - 1;
        float4 u_p4 = *(const float4*)&shr[0][q0];
        float4 w_p4 = *(const float4*)&shr[1][q0];
        float4 u_q4 = *(const float4*)&shr[2][q0];
        float4 w_q4 = *(const float4*)&shr[3][q0];
        float4 duq4 = *(const float4*)&shr[4][q0];
        float4 dwq4 = *(const float4*)&shr[5][q0];
        float4 pp4  = *(const float4*)&shr[6][q0];
        const float ul_q = shr[2][il], ur_q = shr[2][ir];
        const float wl_q = shr[3][il], wr_q = shr[3][ir];

        float4 u_r = avg4(un_r, uo_r), w_r = avg4(wn_r, wo_r);
        float4 du_r = sub4(un_r, uo_r), dw_r = sub4(wn_r, wo_r);
        float4 u_s = avg4(un_s, uo_s), w_s = avg4(wn_s, wo_s);

        float pl_q = __shfl_up(p_q4.w, 1);
        if (lane == 0) pl_q = splq;
        float ul_r = __shfl_up(u_r.w, 1),  wl_r = __shfl_up(w_r.w, 1);
        float pl_r = __shfl_up(p_r4.w, 1);
        if (lane == 0) { ul_r = sulr; wl_r = swlr; pl_r = splr; }
        float ur_r = __shfl_down(u_r.x, 1), wr_r = __shfl_down(w_r.x, 1);
        if (lane == 63) { ur_r = surr; wr_r = swrr; }

        {   // row y+2: ym = LDS row y+1, center = LDS row y+2, yp = own row y+3
            const float uc[6]  = {ul_q, u_q4.x, u_q4.y, u_q4.z, u_q4.w, ur_q};
            const float wcv[6] = {wl_q, w_q4.x, w_q4.y, w_q4.z, w_q4.w, wr_q};
            const float uym[4] = {u_p4.x, u_p4.y, u_p4.z, u_p4.w};
            const float uyp[4] = {u_r.x, u_r.y, u_r.z, u_r.w};
            const float wym[4] = {w_p4.x, w_p4.y, w_p4.z, w_p4.w};
            const float wyp[4] = {w_r.x, w_r.y, w_r.z, w_r.w};
            const float du[4]  = {duq4.x, duq4.y, duq4.z, duq4.w};
            const float dw[4]  = {dwq4.x, dwq4.y, dwq4.z, dwq4.w};
            const float pcv[5] = {pl_q, p_q4.x, p_q4.y, p_q4.z, p_q4.w};
            const float pym[4] = {pp4.x, pp4.y, pp4.z, pp4.w};
            const int   mm[4]  = {m_q4.x, m_q4.y, m_q4.z, m_q4.w};
            acc += row_stencil(uc, wcv, uym, uyp, wym, wyp, du, dw, pcv, pym, mm, q0, rv_q);
        }
        {   // row y+3: ym = LDS row y+2, center/yp = own rows y+3,y+4
            const float uc[6]  = {ul_r, u_r.x, u_r.y, u_r.z, u_r.w, ur_r};
            const float wcv[6] = {wl_r, w_r.x, w_r.y, w_r.z, w_r.w, wr_r};
            const float uym[4] = {u_q4.x, u_q4.y, u_q4.z, u_q4.w};
            const float uyp[4] = {u_s.x, u_s.y, u_s.z, u_s.w};
            const float wym[4] = {w_q4.x, w_q4.y, w_q4.z, w_q4.w};
            const float wyp[4] = {w_s.x, w_s.y, w_s.z, w_s.w};
            const float du[4]  = {du_r.x, du_r.y, du_r.z, du_r.w};
            const float dw[4]  = {dw_r.x, dw_r.y, dw_r.z, dw_r.w};
            const float pcv[5] = {pl_r, p_r4.x, p_r4.y, p_r4.z, p_r4.w};
            const float pym[4] = {p_q4.x, p_q4.y, p_q4.z, p_q4.w};
            const int   mm[4]  = {m_r4.x, m_r4.y, m_r4.z, m_r4.w};
            acc += row_stencil(uc, wcv, uym, uyp, wym, wyp, du, dw, pcv, pym, mm, q0, rv_r);
        }
    }

    // ---- block reduction over 8 waves ----
    #pragma unroll
    for (int off = 32; off > 0; off >>= 1)
        acc += __shfl_down(acc, off);

    if (lane == 0) sred[tid >> 6] = acc;
    __syncthreads();

    if (tid == 0) {
        float s = 0.f;
        #pragma unroll
        for (int i = 0; i < 8; ++i) s += sred[i];
        ws[lg] = s;
    }
}

__global__ __launch_bounds__(256) void ns_loss_reduce(
    const float* __restrict__ ws, float* __restrict__ out)
{
    const int b = blockIdx.x;
    float acc = 0.f;
    for (int i = threadIdx.x; i < PARTS_PER_B; i += 256)
        acc += ws[b * PARTS_PER_B + i];

    #pragma unroll
    for (int off = 32; off > 0; off >>= 1)
        acc += __shfl_down(acc, off);

    __shared__ float smem[4];
    const int lane = threadIdx.x & 63;
    const int wid  = threadIdx.x >> 6;
    if (lane == 0) smem[wid] = acc;
    __syncthreads();

    if (threadIdx.x == 0) {
        const float inv = 1.0f / ((float)(NS_H - 2) * (float)(NS_W - 2));
        out[b] = (smem[0] + smem[1] + smem[2] + smem[3]) * inv;
    }
}

extern "C" void kernel_launch(void* const* d_in, const int* in_sizes, int n_in,
                              void* d_out, int out_size, void* d_ws, size_t ws_size,
                              hipStream_t stream) {
    const float* v_old = (const float*)d_in[0];
    const float* v_new = (const float*)d_in[1];
    const float* p_new = (const float*)d_in[2];
    const int*   msk   = (const int*)d_in[3];
    float* out = (float*)d_out;
    float* ws  = (float*)d_ws;

    ns_loss_partial<<<dim3(NBLK), dim3(512), 0, stream>>>(v_old, v_new, p_new, msk, ws);
    ns_loss_reduce<<<dim3(8), dim3(256), 0, stream>>>(ws, out);
}